// Round 4
// baseline (2889.922 us; speedup 1.0000x reference)
//
#include <hip/hip_runtime.h>

#define N_NODES 50000
#define L_SCALES 4
#define E_NNZ 1600000
#define C 128
#define ELL_W 64
#define OVF_CAP 8192

// ---------------- GEMM: Y[row,c] = sum_k feat[row,l,k] * W[k,c] ----------------
__global__ __launch_bounds__(256) void gemm_kernel(
    const float* __restrict__ feat,   // [N, L, C]
    const float* __restrict__ W,      // [C, C]
    float* __restrict__ Y,            // [N, C]
    int l)
{
    __shared__ float Ws[32 * C];      // 16 KB k-tile of W
    __shared__ float Xs[16 * C];      // 8 KB: 16 feature rows

    int t = threadIdx.x;
    int row0 = blockIdx.x * 16;

    for (int i = t; i < 16 * C; i += 256) {
        int r = row0 + (i >> 7);
        Xs[i] = (r < N_NODES) ? feat[((size_t)r * L_SCALES + l) * C + (i & 127)] : 0.f;
    }

    int rr = t >> 4;            // local row 0..15
    int c0 = (t & 15) * 8;      // channel group
    float acc[8] = {0.f, 0.f, 0.f, 0.f, 0.f, 0.f, 0.f, 0.f};

    for (int kt = 0; kt < 4; ++kt) {
        __syncthreads();
        for (int i = t; i < 32 * C; i += 256)
            Ws[i] = W[kt * 32 * C + i];
        __syncthreads();
        #pragma unroll
        for (int k = 0; k < 32; ++k) {
            float x = Xs[rr * C + kt * 32 + k];
            #pragma unroll
            for (int j = 0; j < 8; ++j)
                acc[j] += x * Ws[k * C + c0 + j];
        }
    }

    int row = row0 + rr;
    if (row < N_NODES) {
        #pragma unroll
        for (int j = 0; j < 8; ++j)
            Y[(size_t)row * C + c0 + j] = acc[j];
    }
}

// ---------------- ELL build (edge-ID only, both matrices in one kernel) ----------------
__global__ __launch_bounds__(256) void build_ell2(
    const int* __restrict__ rowsA,   // phi_inv rows [E]
    const int* __restrict__ rowsB,   // phi rows [E]
    int* __restrict__ cntA, int* __restrict__ cntB,        // [N] each, pre-zeroed
    int* __restrict__ ellA, int* __restrict__ ellB,        // [N*ELL_W] each (edge ids)
    int* __restrict__ ovfA_n, int* __restrict__ ovfA_row, int* __restrict__ ovfA_eid,
    int* __restrict__ ovfB_n, int* __restrict__ ovfB_row, int* __restrict__ ovfB_eid)
{
    int idx = blockIdx.x * blockDim.x + threadIdx.x;
    if (idx < E_NNZ) {
        int e = idx;
        int r = rowsA[e];
        int pos = atomicAdd(&cntA[r], 1);
        if (pos < ELL_W) {
            ellA[(size_t)r * ELL_W + pos] = e;
        } else {
            int k = atomicAdd(ovfA_n, 1);
            if (k < OVF_CAP) { ovfA_row[k] = r; ovfA_eid[k] = e; }
        }
    } else {
        int e = idx - E_NNZ;
        if (e >= E_NNZ) return;
        int r = rowsB[e];
        int pos = atomicAdd(&cntB[r], 1);
        if (pos < ELL_W) {
            ellB[(size_t)r * ELL_W + pos] = e;
        } else {
            int k = atomicAdd(ovfB_n, 1);
            if (k < OVF_CAP) { ovfB_row[k] = r; ovfB_eid[k] = e; }
        }
    }
}

// ---------------- SpMM (gather): out[row] = (row_scale?) * sum_e val_e * X[col_e] ----------------
// One wave per row; lane j preloads edge j's (col,val) via eid; shfl-broadcast; float2/lane.
__global__ __launch_bounds__(256) void spmm_ell(
    const int*   __restrict__ ell,        // [N*ELL_W] edge ids
    const int*   __restrict__ cnt,        // [N]
    const int*   __restrict__ cols,       // [E]
    const float* __restrict__ vals,       // [E]
    const int*   __restrict__ ovf_n,
    const int*   __restrict__ ovf_row,
    const int*   __restrict__ ovf_eid,
    const float* __restrict__ X,          // [N, C]
    const float* __restrict__ row_scale,  // nullptr or theta[N]
    float*       __restrict__ out,        // base (maybe offset)
    int out_stride)
{
    int row  = (blockIdx.x * 256 + threadIdx.x) >> 6;
    int lane = threadIdx.x & 63;
    if (row >= N_NODES) return;

    int n   = cnt[row];
    int ncl = n < ELL_W ? n : ELL_W;

    int eid = 0;
    if (lane < ncl) eid = ell[(size_t)row * ELL_W + lane];   // coalesced 4B
    int   mycol = cols[eid];
    float myval = vals[eid];

    float2 acc = {0.f, 0.f};
    for (int j = 0; j < ncl; ++j) {
        int   c = __shfl(mycol, j);
        float v = __shfl(myval, j);
        float2 x = ((const float2*)(X + (size_t)c * C))[lane];
        acc.x += v * x.x;
        acc.y += v * x.y;
    }

    if (n > ELL_W) {   // astronomically rare; correctness fallback
        int m = *ovf_n;
        if (m > OVF_CAP) m = OVF_CAP;
        for (int k = 0; k < m; ++k) {
            if (ovf_row[k] == row) {
                int   e = ovf_eid[k];
                int   c = cols[e];
                float v = vals[e];
                float2 x = ((const float2*)(X + (size_t)c * C))[lane];
                acc.x += v * x.x;
                acc.y += v * x.y;
            }
        }
    }

    if (row_scale) {
        float s = row_scale[row];
        acc.x *= s;
        acc.y *= s;
    }
    ((float2*)(out + (size_t)row * out_stride))[lane] = acc;
}

extern "C" void kernel_launch(void* const* d_in, const int* in_sizes, int n_in,
                              void* d_out, int out_size, void* d_ws, size_t ws_size,
                              hipStream_t stream) {
    const int*   phi_idx  = (const int*)  d_in[0];   // [L, 2, E]
    const float* phi_val  = (const float*)d_in[1];   // [L, E]
    const int*   pinv_idx = (const int*)  d_in[2];   // [L, 2, E]
    const float* pinv_val = (const float*)d_in[3];   // [L, E]
    const float* feat     = (const float*)d_in[4];   // [N, L, C]
    const float* W        = (const float*)d_in[5];   // [C, C]
    const float* theta    = (const float*)d_in[6];   // [N]
    float* out = (float*)d_out;

    // Workspace layout (~77.3 MB). cntA,cntB,ovfA_n,ovfB_n are contiguous
    // so one memset zeroes all four.
    float* Y    = (float*)d_ws;                        // N*C floats
    float* Z    = Y + (size_t)N_NODES * C;             // N*C floats
    int* ellA   = (int*)(Z + (size_t)N_NODES * C);     // N*ELL_W ints
    int* ellB   = ellA + (size_t)N_NODES * ELL_W;      // N*ELL_W ints
    int* cntA   = ellB + (size_t)N_NODES * ELL_W;      // N ints
    int* cntB   = cntA + N_NODES;                      // N ints
    int* ovfA_n = cntB + N_NODES;                      // 1 int
    int* ovfB_n = ovfA_n + 1;                          // 1 int
    int* ovfA_row = ovfB_n + 1;
    int* ovfA_eid = ovfA_row + OVF_CAP;
    int* ovfB_row = ovfA_eid + OVF_CAP;
    int* ovfB_eid = ovfB_row + OVF_CAP;

    dim3 gemmGrid((N_NODES + 15) / 16);
    dim3 buildGrid((2 * E_NNZ + 255) / 256);
    dim3 spmmGrid((N_NODES * 64 + 255) / 256);   // one wave per row

    for (int l = 0; l < L_SCALES; ++l) {
        // Y = feat[:, l, :] @ W
        gemm_kernel<<<gemmGrid, 256, 0, stream>>>(feat, W, Y, l);

        // zero both counters + both overflow counts in one memset
        (void)hipMemsetAsync(cntA, 0, (2 * N_NODES + 2) * sizeof(int), stream);

        // bucket both matrices' edges by row (edge ids only)
        build_ell2<<<buildGrid, 256, 0, stream>>>(
            pinv_idx + (size_t)l * 2 * E_NNZ,          // phi_inv rows
            phi_idx  + (size_t)l * 2 * E_NNZ,          // phi rows
            cntA, cntB, ellA, ellB,
            ovfA_n, ovfA_row, ovfA_eid,
            ovfB_n, ovfB_row, ovfB_eid);

        // Z = theta ⊙ (phi_inv_l @ Y)
        spmm_ell<<<spmmGrid, 256, 0, stream>>>(
            ellA, cntA,
            pinv_idx + (size_t)l * 2 * E_NNZ + E_NNZ,  // cols
            pinv_val + (size_t)l * E_NNZ,
            ovfA_n, ovfA_row, ovfA_eid,
            Y, theta, Z, C);

        // out[:, l, :] = phi_l @ Z
        spmm_ell<<<spmmGrid, 256, 0, stream>>>(
            ellB, cntB,
            phi_idx + (size_t)l * 2 * E_NNZ + E_NNZ,
            phi_val + (size_t)l * E_NNZ,
            ovfB_n, ovfB_row, ovfB_eid,
            Z, nullptr, out + l * C, L_SCALES * C);
    }
}